// Round 7
// baseline (97.688 us; speedup 1.0000x reference)
//
#include <hip/hip_runtime.h>
#include <math.h>

// CapsuleLayer dynamic routing. B=256, IN=1152, K=8, J=10, D=16, 3 passes.
//
// prep_all : coalesced LDS-transpose preps.
//   wht bf16 [i][jd][k0..7] = W[i][j][k][d] * 0.25 (k-replication trick:
//   all 4 K-quads of the MFMA load the same 8-k fragment -> u = 4*(x*W/4)).
//   xht bf16 [i][b][k0..7] = x[b][i][k].
// caps_pass<P>: grid (72 i-slabs x 16 b-tiles), 256 thr = 4 waves.
//   Block covers 16 i (2 slices of 8 staged to LDS) x 16 b. Wave w owns
//   i's {w*2, w*2+1} per slice. Per i: 10x mfma_f32_16x16x32_bf16
//   (A = W-tile bcast over quads, B = x bcast over quads). C layout:
//   b = lane&15, d = (lane>>4)*4+reg, j = tile (HW-verified, r5/r6 passed).
//   Logit = 4 in-lane FMA + shfl_xor 16/32; softmax in-lane; s in regs;
//   4-wave LDS tree reduce -> one s_part slab per block. No atomics.
// k_squash<P>: reduce 72 slabs + squash -> vdot / out.
// Algebra: logits at pass t = (sum of previous v)·u_hat; pass 0 c = 0.1.

typedef float f32x4 __attribute__((ext_vector_type(4)));
typedef short bf16x8 __attribute__((ext_vector_type(8)));

#define B_TOT 256
#define IN_CAPS 1152
#define OUT_CAPS 10
#define OUT_DIM 16
#define JD 160

#define NSLAB 72           // i-slabs (16 i each)
#define REDS 164           // reduce row stride (floats, mult of 4)

#define WHT_BYTES (1152ull * 160 * 8 * 2)                 // 2,949,120
#define XHT_BYTES (1152ull * 256 * 8 * 2)                 // 4,718,592
#define SP_BYTES  ((size_t)NSLAB * B_TOT * JD * 4)        // 11,796,480
#define VD_BYTES  ((size_t)B_TOT * JD * 4)                // 163,840
#define WS_NEED   (WHT_BYTES + XHT_BYTES + SP_BYTES + VD_BYTES)

static __device__ __forceinline__ unsigned f2bf(float f) {
    unsigned u = __float_as_uint(f);
    return (u + 0x7FFFu + ((u >> 16) & 1u)) >> 16;
}

// ---------------- coalesced preps ----------------
#define PREPW_BLOCKS 288   // 4 i each
#define PREPX_BLOCKS 288   // 16 i x 64 b each

__global__ __launch_bounds__(256)
void prep_all(const float* __restrict__ x, const float* __restrict__ W,
              unsigned* __restrict__ whu, unsigned* __restrict__ xhu) {
    __shared__ __align__(16) float lds[64 * 132];   // 33,792 B
    const int bid = blockIdx.x, t = threadIdx.x;

    if (bid < PREPW_BLOCKS) {
        // ---- W path: 4 i per block ----
        const int i0 = bid * 4;
        const f32x4* src = (const f32x4*)(W + (size_t)i0 * 1280);
        for (int c = t; c < 1280; c += 256)
            *(f32x4*)(lds + c * 4) = src[c];          // coalesced read, linear LDS
        __syncthreads();
        for (int c = t; c < 2560; c += 256) {
            const int i_l = c / 640, p = c % 640;
            const int jd = p >> 2, kp = p & 3;        // k = 2*kp
            const int j = jd >> 4, d = jd & 15;
            const float* base = lds + i_l * 1280 + j * 128 + d;
            const unsigned lo = f2bf(base[(2 * kp) * 16] * 0.25f);
            const unsigned hi = f2bf(base[(2 * kp + 1) * 16] * 0.25f);
            whu[(size_t)i0 * 640 + c] = lo | (hi << 16);   // coalesced write
        }
    } else {
        // ---- x path: 16 i x 64 b tile ----
        const int bx = bid - PREPW_BLOCKS;
        const int it = bx >> 2;          // 72 i-tiles
        const int bt = bx & 3;           // 4 b-tiles of 64
        const int i0 = it * 16, b0 = bt * 64;
        for (int c = t; c < 2048; c += 256) {
            const int bl = c >> 5, cf = c & 31;
            f32x4 v = *(const f32x4*)(x + (size_t)(b0 + bl) * 9216 + i0 * 8 + cf * 4);
            *(f32x4*)(lds + bl * 132 + cf * 4) = v;   // coalesced read (512B runs/b)
        }
        __syncthreads();
        for (int c = t; c < 1024; c += 256) {
            const int i_l = c >> 6, b_l = c & 63;
            const float* r = lds + b_l * 132 + i_l * 8;
            uint4 o;
            o.x = f2bf(r[0]) | (f2bf(r[1]) << 16);
            o.y = f2bf(r[2]) | (f2bf(r[3]) << 16);
            o.z = f2bf(r[4]) | (f2bf(r[5]) << 16);
            o.w = f2bf(r[6]) | (f2bf(r[7]) << 16);
            ((uint4*)xhu)[(size_t)(i0 + i_l) * 256 + b0 + b_l] = o;  // 1KB runs
        }
    }
}

// ---------------- routing pass ----------------
template<int PASS>
__global__ __launch_bounds__(256, 3)
void caps_pass(const unsigned short* __restrict__ wht,
               const unsigned short* __restrict__ xht,
               const float* __restrict__ vdot,
               float* __restrict__ s_part) {
    __shared__ __align__(16) unsigned short wsl[8 * 1280];   // 20,480 B (one 8-i slice)
    __shared__ __align__(16) unsigned short xsl[8 * 16 * 8]; //  2,048 B
    __shared__ __align__(16) float red[2 * 16 * REDS];       // 20,992 B

    const int t  = threadIdx.x;
    const int l  = t & 63;
    const int w  = t >> 6;              // wave 0..3 (splits i)
    const int m  = l & 15;              // b within tile / A-row / C-col
    const int q  = l >> 4;              // k-quad (replicated) / d-quad (out)
    const int islab = blockIdx.x;       // 0..71
    const int b0 = blockIdx.y * 16;
    const int b  = b0 + m;

    // vdot fragments, i-invariant (PASS >= 1)
    f32x4 vd[10];
    if (PASS > 0) {
        #pragma unroll
        for (int jt = 0; jt < 10; ++jt)
            vd[jt] = *(const f32x4*)(vdot + (size_t)b * JD + jt * 16 + q * 4);
    }

    f32x4 s[10];
    #pragma unroll
    for (int jt = 0; jt < 10; ++jt) s[jt] = (f32x4){0.f, 0.f, 0.f, 0.f};

    #pragma unroll 1
    for (int sl = 0; sl < 2; ++sl) {
        const int i0 = islab * 16 + sl * 8;
        __syncthreads();
        // stage W slice: 8 i x 640 u32 = 1280 uint4, coalesced
        {
            const uint4* src = (const uint4*)(wht + (size_t)i0 * 1280);
            uint4* dst = (uint4*)wsl;
            for (int c = t; c < 1280; c += 256) dst[c] = src[c];
        }
        // stage x slice: 8 i x 16 b = 128 uint4
        if (t < 128) {
            const int il = t >> 4, bl = t & 15;
            ((uint4*)xsl)[t] = ((const uint4*)xht)[(size_t)(i0 + il) * 256 + b0 + bl];
        }
        __syncthreads();

        #pragma unroll 1
        for (int ii = 0; ii < 2; ++ii) {
            const int il = w * 2 + ii;

            // B-frag: x[b][i][k0..7], replicated across quads (bank-friendly bcast)
            const bf16x8 xb = *(const bf16x8*)(xsl + (il * 16 + m) * 8);

            f32x4 u[10];
            #pragma unroll
            for (int jt = 0; jt < 10; ++jt) {
                const bf16x8 af = *(const bf16x8*)(wsl + (il * 160 + jt * 16 + m) * 8);
                u[jt] = __builtin_amdgcn_mfma_f32_16x16x32_bf16(
                            af, xb, (f32x4){0.f, 0.f, 0.f, 0.f}, 0, 0, 0);
            }

            if (PASS == 0) {
                #pragma unroll
                for (int jt = 0; jt < 10; ++jt) s[jt] += 0.1f * u[jt];
            } else {
                float L[10];
                #pragma unroll
                for (int jt = 0; jt < 10; ++jt) {
                    const f32x4 p = vd[jt] * u[jt];
                    float e = (p.x + p.y) + (p.z + p.w);
                    e += __shfl_xor(e, 16);
                    e += __shfl_xor(e, 32);
                    L[jt] = e;
                }
                float mx = L[0];
                #pragma unroll
                for (int jt = 1; jt < 10; ++jt) mx = fmaxf(mx, L[jt]);
                float Z = 0.f;
                #pragma unroll
                for (int jt = 0; jt < 10; ++jt) { L[jt] = __expf(L[jt] - mx); Z += L[jt]; }
                const float inv = 1.0f / Z;
                #pragma unroll
                for (int jt = 0; jt < 10; ++jt) s[jt] += (L[jt] * inv) * u[jt];
            }
        }
    }

    // ---- 4-wave tree reduce through LDS ----
    __syncthreads();
    if (w >= 2) {
        float* rp = red + (w - 2) * (16 * REDS) + m * REDS + q * 4;
        #pragma unroll
        for (int jt = 0; jt < 10; ++jt) *(f32x4*)(rp + jt * 16) = s[jt];
    }
    __syncthreads();
    if (w < 2) {
        const float* rp = red + w * (16 * REDS) + m * REDS + q * 4;
        #pragma unroll
        for (int jt = 0; jt < 10; ++jt) s[jt] += *(const f32x4*)(rp + jt * 16);
    }
    __syncthreads();
    if (w == 1) {
        float* rp = red + m * REDS + q * 4;
        #pragma unroll
        for (int jt = 0; jt < 10; ++jt) *(f32x4*)(rp + jt * 16) = s[jt];
    }
    __syncthreads();
    if (w == 0) {
        const float* rp = red + m * REDS + q * 4;
        #pragma unroll
        for (int jt = 0; jt < 10; ++jt) s[jt] += *(const f32x4*)(rp + jt * 16);
        float* sp = s_part + ((size_t)islab * B_TOT + b) * JD;
        #pragma unroll
        for (int jt = 0; jt < 10; ++jt)
            *(f32x4*)(sp + jt * 16 + q * 4) = s[jt];
    }
}

// ---------------- reduce + squash ----------------
template<int PASS>
__global__ __launch_bounds__(256)
void k_squash(const float* __restrict__ s_part,
              float* __restrict__ vdot, float* __restrict__ out) {
    const int e = blockIdx.x * 256 + threadIdx.x;    // < 40960
    float s = 0.f;
    #pragma unroll 8
    for (int p = 0; p < NSLAB; ++p)
        s += s_part[(size_t)p * (B_TOT * JD) + e];

    float t = s * s;
    t += __shfl_xor(t, 1);
    t += __shfl_xor(t, 2);
    t += __shfl_xor(t, 4);
    t += __shfl_xor(t, 8);
    const float scale = t / (1.0f + t) / sqrtf(t + 1e-7f);
    const float v = scale * s;

    if (PASS == 0)      vdot[e] = v;
    else if (PASS == 1) vdot[e] += v;
    else                out[e] = v;
}

// ---------- fallback: round-1 fused kernel (ws too small; shouldn't happen) ----------
#define FB_NGROUPS 32
#define FB_THREADS (FB_NGROUPS * OUT_DIM)
#define FB_ITERS (IN_CAPS / FB_NGROUPS)
__global__ __launch_bounds__(FB_THREADS)
void caps_routing_kernel(const float* __restrict__ x, const float* __restrict__ W,
                         float* __restrict__ out) {
    __shared__ __align__(16) float xsf[IN_CAPS * 8];
    __shared__ float sredf[FB_NGROUPS * JD];
    __shared__ float vdot_lds[JD];
    const int b = blockIdx.x, tid = threadIdx.x;
    const int g = tid >> 4, d = tid & 15;
    {
        const float4* xg = reinterpret_cast<const float4*>(x + (size_t)b * IN_CAPS * 8);
        float4* xl = reinterpret_cast<float4*>(xsf);
        for (int t = tid; t < IN_CAPS * 2; t += FB_THREADS) xl[t] = xg[t];
    }
    __syncthreads();
    for (int pass = 0; pass < 3; ++pass) {
        float vdot_reg[OUT_CAPS];
        if (pass > 0) {
            #pragma unroll
            for (int j = 0; j < OUT_CAPS; ++j) vdot_reg[j] = vdot_lds[j * OUT_DIM + d];
        }
        float s_loc[OUT_CAPS];
        #pragma unroll
        for (int j = 0; j < OUT_CAPS; ++j) s_loc[j] = 0.f;
        for (int it = 0; it < FB_ITERS; ++it) {
            const int i = it * FB_NGROUPS + g;
            float xk[8];
            {
                const float4* xr = reinterpret_cast<const float4*>(xsf + i * 8);
                float4 a0 = xr[0], a1 = xr[1];
                xk[0]=a0.x; xk[1]=a0.y; xk[2]=a0.z; xk[3]=a0.w;
                xk[4]=a1.x; xk[5]=a1.y; xk[6]=a1.z; xk[7]=a1.w;
            }
            const float* wpf = W + (size_t)i * 1280 + d;
            float u[OUT_CAPS];
            #pragma unroll
            for (int j = 0; j < OUT_CAPS; ++j) {
                float acc = 0.f;
                #pragma unroll
                for (int k = 0; k < 8; ++k) acc = fmaf(xk[k], wpf[j * 128 + k * OUT_DIM], acc);
                u[j] = acc;
            }
            if (pass == 0) {
                #pragma unroll
                for (int j = 0; j < OUT_CAPS; ++j) s_loc[j] = fmaf(0.1f, u[j], s_loc[j]);
            } else {
                float logit[OUT_CAPS];
                #pragma unroll
                for (int j = 0; j < OUT_CAPS; ++j) {
                    float t2 = vdot_reg[j] * u[j];
                    t2 += __shfl_xor(t2, 1); t2 += __shfl_xor(t2, 2);
                    t2 += __shfl_xor(t2, 4); t2 += __shfl_xor(t2, 8);
                    logit[j] = t2;
                }
                float m = logit[0];
                #pragma unroll
                for (int j = 1; j < OUT_CAPS; ++j) m = fmaxf(m, logit[j]);
                float Z = 0.f, e[OUT_CAPS];
                #pragma unroll
                for (int j = 0; j < OUT_CAPS; ++j) { e[j] = expf(logit[j] - m); Z += e[j]; }
                const float invZ = 1.0f / Z;
                #pragma unroll
                for (int j = 0; j < OUT_CAPS; ++j) s_loc[j] = fmaf(e[j] * invZ, u[j], s_loc[j]);
            }
        }
        #pragma unroll
        for (int j = 0; j < OUT_CAPS; ++j) sredf[g * JD + j * OUT_DIM + d] = s_loc[j];
        __syncthreads();
        if (tid < JD) {
            float sv = 0.f;
            #pragma unroll 8
            for (int gg = 0; gg < FB_NGROUPS; ++gg) sv += sredf[gg * JD + tid];
            float t2 = sv * sv;
            t2 += __shfl_xor(t2, 1); t2 += __shfl_xor(t2, 2);
            t2 += __shfl_xor(t2, 4); t2 += __shfl_xor(t2, 8);
            const float scale = t2 / (1.0f + t2) / sqrtf(t2 + 1e-7f);
            const float v = scale * sv;
            if (pass == 2) out[(size_t)b * JD + tid] = v;
            else vdot_lds[tid] = (pass == 0) ? v : (vdot_lds[tid] + v);
        }
        __syncthreads();
    }
}

extern "C" void kernel_launch(void* const* d_in, const int* in_sizes, int n_in,
                              void* d_out, int out_size, void* d_ws, size_t ws_size,
                              hipStream_t stream) {
    const float* x = (const float*)d_in[0];
    const float* W = (const float*)d_in[1];
    float* out = (float*)d_out;

    if (ws_size >= WS_NEED) {
        unsigned short* wht = (unsigned short*)d_ws;
        unsigned short* xht = (unsigned short*)((char*)d_ws + WHT_BYTES);
        float* s_part = (float*)((char*)d_ws + WHT_BYTES + XHT_BYTES);
        float* vdot   = (float*)((char*)d_ws + WHT_BYTES + XHT_BYTES + SP_BYTES);

        prep_all<<<PREPW_BLOCKS + PREPX_BLOCKS, 256, 0, stream>>>(
            x, W, (unsigned*)wht, (unsigned*)xht);

        const dim3 gR(NSLAB, 16);
        const int gSQ = (B_TOT * JD) / 256;   // 160

        caps_pass<0><<<gR, 256, 0, stream>>>(wht, xht, vdot, s_part);
        k_squash<0><<<gSQ, 256, 0, stream>>>(s_part, vdot, out);
        caps_pass<1><<<gR, 256, 0, stream>>>(wht, xht, vdot, s_part);
        k_squash<1><<<gSQ, 256, 0, stream>>>(s_part, vdot, out);
        caps_pass<2><<<gR, 256, 0, stream>>>(wht, xht, vdot, s_part);
        k_squash<2><<<gSQ, 256, 0, stream>>>(s_part, vdot, out);
    } else {
        caps_routing_kernel<<<B_TOT, FB_THREADS, 0, stream>>>(x, W, out);
    }
}